// Round 1
// baseline (566.003 us; speedup 1.0000x reference)
//
#include <hip/hip_runtime.h>

// AfmoeAttention on MI355X (gfx950), round 0.
// Pipeline: cvt(f32->bf16) -> fused QKVG GEMM (bf16 MFMA 16x16x32, m97-style)
//           -> RMSNorm+RoPE+transpose prep -> flash attention (GQA, fused
//           sigmoid-gate epilogue) -> output GEMM (f32 out).

#define LOG2E 1.44269504088896340736f

typedef __attribute__((ext_vector_type(4))) float f32x4;
typedef __attribute__((ext_vector_type(8))) short bf16x8;   // 8 x bf16 (4 VGPRs)

__device__ __forceinline__ float bf2f(unsigned short u) {
  union { unsigned u; float f; } x; x.u = ((unsigned)u) << 16; return x.f;
}
__device__ __forceinline__ unsigned short f2bf(float f) {
  union { float f; unsigned u; } x; x.f = f;
  unsigned r = x.u + 0x7fffu + ((x.u >> 16) & 1u);   // RNE
  return (unsigned short)(r >> 16);
}

// async global->LDS, 16B per lane. LDS dest = wave-uniform base + lane*16.
__device__ __forceinline__ void async16(void* lds, const void* g) {
  __builtin_amdgcn_global_load_lds(
      (const __attribute__((address_space(1))) unsigned*)g,
      (__attribute__((address_space(3))) unsigned*)lds, 16, 0, 0);
}

// ---------------------------------------------------------------- cvt kernel
__global__ __launch_bounds__(256) void cvt_f32_bf16(
    const float* __restrict__ src, unsigned short* __restrict__ dst, int n4) {
  int i = blockIdx.x * 256 + threadIdx.x;
  if (i >= n4) return;
  float4 v = reinterpret_cast<const float4*>(src)[i];
  ushort4 u;
  u.x = f2bf(v.x); u.y = f2bf(v.y); u.z = f2bf(v.z); u.w = f2bf(v.w);
  reinterpret_cast<ushort4*>(dst)[i] = u;
}

// ------------------------------------------------------------- GEMM template
// C[M,N] = A[M,K] @ W[N,K]^T, 128x128 tile, BK=32, 4 waves each 64x64.
template <typename CT>
__device__ __forceinline__ void gemm128(
    const unsigned short* __restrict__ A, const unsigned short* __restrict__ W,
    CT* __restrict__ C, int m0, int n0, int ldc, int K,
    unsigned short* As, unsigned short* Bs) {
  const int tid = threadIdx.x;
  const int w = tid >> 6, l = tid & 63, quad = l >> 4, l16 = l & 15;
  const int wm = (w & 1) * 64, wn = (w >> 1) * 64;

  f32x4 acc[4][4];
  const f32x4 Z4 = {0.f, 0.f, 0.f, 0.f};
#pragma unroll
  for (int i = 0; i < 4; i++)
#pragma unroll
    for (int j = 0; j < 4; j++) acc[i][j] = Z4;

  const int srow = tid >> 2;            // 0..63
  const int scol = (tid & 3) * 8;       // elem offset in K
  const unsigned short* gA = A + (size_t)(m0 + srow) * K + scol;
  const unsigned short* gB = W + (size_t)(n0 + srow) * K + scol;
  unsigned short* lA = As + tid * 8;    // byte offset tid*16
  unsigned short* lB = Bs + tid * 8;

  for (int kb = 0; kb < K; kb += 32) {
    async16(lA,        gA + kb);
    async16(lA + 2048, gA + (size_t)64 * K + kb);
    async16(lB,        gB + kb);
    async16(lB + 2048, gB + (size_t)64 * K + kb);
    __syncthreads();   // waits vmcnt(0): async LDS writes landed

    bf16x8 af[4], bf[4];
#pragma unroll
    for (int mt = 0; mt < 4; mt++)
      af[mt] = *(const bf16x8*)&As[(wm + mt * 16 + l16) * 32 + quad * 8];
#pragma unroll
    for (int nt = 0; nt < 4; nt++)
      bf[nt] = *(const bf16x8*)&Bs[(wn + nt * 16 + l16) * 32 + quad * 8];
#pragma unroll
    for (int mt = 0; mt < 4; mt++)
#pragma unroll
      for (int nt = 0; nt < 4; nt++)
        acc[mt][nt] = __builtin_amdgcn_mfma_f32_16x16x32_bf16(
            af[mt], bf[nt], acc[mt][nt], 0, 0, 0);
    __syncthreads();   // all reads done before next tile's staging
  }

  // C/D layout: col = lane&15, row = quad*4 + reg
#pragma unroll
  for (int mt = 0; mt < 4; mt++)
#pragma unroll
    for (int nt = 0; nt < 4; nt++) {
      int row = m0 + wm + mt * 16 + quad * 4;
      int col = n0 + wn + nt * 16 + l16;
#pragma unroll
      for (int r = 0; r < 4; r++) {
        if constexpr (sizeof(CT) == 2)
          C[(size_t)(row + r) * ldc + col] = f2bf(acc[mt][nt][r]);
        else
          C[(size_t)(row + r) * ldc + col] = acc[mt][nt][r];
      }
    }
}

__global__ __launch_bounds__(256) void gemm_qkvg(
    const unsigned short* __restrict__ X,
    const unsigned short* __restrict__ Wq, const unsigned short* __restrict__ Wk,
    const unsigned short* __restrict__ Wv, const unsigned short* __restrict__ Wg,
    unsigned short* __restrict__ Qr, unsigned short* __restrict__ Kr,
    unsigned short* __restrict__ Vr, unsigned short* __restrict__ Gr) {
  __shared__ __attribute__((aligned(16))) unsigned short As[128 * 32];
  __shared__ __attribute__((aligned(16))) unsigned short Bs[128 * 32];
  int ny = blockIdx.y;
  const unsigned short* W; unsigned short* C; int n0, ldc;
  if (ny < 16)      { W = Wq; C = Qr; n0 = ny * 128;        ldc = 2048; }
  else if (ny < 18) { W = Wk; C = Kr; n0 = (ny - 16) * 128; ldc = 256;  }
  else if (ny < 20) { W = Wv; C = Vr; n0 = (ny - 18) * 128; ldc = 256;  }
  else              { W = Wg; C = Gr; n0 = (ny - 20) * 128; ldc = 2048; }
  gemm128<unsigned short>(X, W, C, blockIdx.x * 128, n0, ldc, 2048, As, Bs);
}

__global__ __launch_bounds__(256) void gemm_out_k(
    const unsigned short* __restrict__ A, const unsigned short* __restrict__ W,
    float* __restrict__ C) {
  __shared__ __attribute__((aligned(16))) unsigned short As[128 * 32];
  __shared__ __attribute__((aligned(16))) unsigned short Bs[128 * 32];
  gemm128<float>(A, W, C, blockIdx.x * 128, blockIdx.y * 128, 2048, 2048, As, Bs);
}

// ------------------------------------------------------ RMSNorm+RoPE+transpose
// unit 0..31: Q head -> Qn[b][h][s][d]  (scaled by 1/8, attention scaling folded)
// unit 32..35: K kv-head -> Kn[b][kv][s][d]
// unit 36..39: V kv-head -> Vt[b][kv][d][s]  (transposed for MFMA B-operand)
__global__ __launch_bounds__(256) void prep_qkv(
    const unsigned short* __restrict__ Qr, const unsigned short* __restrict__ Kr,
    const unsigned short* __restrict__ Vr,
    const float* __restrict__ cosb, const float* __restrict__ sinb,
    const float* __restrict__ qg, const float* __restrict__ kg,
    unsigned short* __restrict__ Qn, unsigned short* __restrict__ Kn,
    unsigned short* __restrict__ Vt) {
  int idx = blockIdx.x * 4 + (threadIdx.x >> 6);   // global unit index
  int d = threadIdx.x & 63;
  int token = idx / 40;
  int unit = idx - token * 40;
  int b = token >> 11, s = token & 2047;

  if (unit >= 36) {   // V transpose (scattered 2B stores, small total)
    int kvh = unit - 36;
    Vt[((size_t)(b * 4 + kvh) * 64 + d) * 2048 + s] =
        Vr[(size_t)token * 256 + kvh * 64 + d];
    return;
  }
  const unsigned short* src; const float* gamma; float scale; unsigned short* dst;
  if (unit < 32) {
    src = Qr + (size_t)token * 2048 + unit * 64;
    gamma = qg; scale = 0.125f;               // 1/sqrt(D)
    dst = Qn + ((size_t)(b * 32 + unit) * 2048 + s) * 64;
  } else {
    int kvh = unit - 32;
    src = Kr + (size_t)token * 256 + kvh * 64;
    gamma = kg; scale = 1.0f;
    dst = Kn + ((size_t)(b * 4 + kvh) * 2048 + s) * 64;
  }
  float x = bf2f(src[d]);
  float ss = x * x;
#pragma unroll
  for (int off = 32; off >= 1; off >>= 1) ss += __shfl_xor(ss, off);
  float rr = rsqrtf(ss * (1.0f / 64.0f) + 1e-6f);
  float xn = x * rr * gamma[d];
  float other = __shfl_xor(xn, 32);           // partner at d^32
  float rot = (d < 32) ? -other : other;      // rotate_half
  size_t cs = (size_t)(b * 2048 + s) * 64 + d;
  dst[d] = f2bf((xn * cosb[cs] + rot * sinb[cs]) * scale);
}

// ---------------------------------------------------------- flash attention
// grid: (S/128, B*NH). 4 waves, each owns 32 Q rows. KV tiles of 128.
__global__ __launch_bounds__(256) void attn(
    const unsigned short* __restrict__ Qn, const unsigned short* __restrict__ Kn,
    const unsigned short* __restrict__ Vt, const unsigned short* __restrict__ gate,
    unsigned short* __restrict__ act) {
  __shared__ __attribute__((aligned(16))) unsigned short smem[32768];  // 64 KB
  unsigned short* Qs  = smem;           // [128][64] (prologue only)
  unsigned short* Ks  = smem;           // [128][64] (reuses Qs region)
  unsigned short* Vts = smem + 8192;    // [64][128]
  unsigned short* Ps  = smem + 16384;   // [128][128], per-wave-private rows

  const int tid = threadIdx.x, w = tid >> 6, l = tid & 63;
  const int quad = l >> 4, l16 = l & 15;
  const int bh = blockIdx.y, b = bh >> 5, h = bh & 31, kvh = h >> 3;
  const int q0 = blockIdx.x * 128;

  const unsigned short* Qg = Qn + ((size_t)(b * 32 + h) * 2048 + q0) * 64;
  const unsigned short* Kg = Kn + (size_t)(b * 4 + kvh) * 2048 * 64;
  const unsigned short* Vg = Vt + (size_t)(b * 4 + kvh) * 64 * 2048;

#pragma unroll
  for (int i = 0; i < 4; i++)
    async16(Qs + i * 2048 + tid * 8,
            Qg + (size_t)(i * 32 + (tid >> 3)) * 64 + (tid & 7) * 8);
  __syncthreads();
  bf16x8 qf[2][2];
#pragma unroll
  for (int mt = 0; mt < 2; mt++)
#pragma unroll
    for (int ks = 0; ks < 2; ks++)
      qf[mt][ks] = *(const bf16x8*)&Qs[(w * 32 + mt * 16 + l16) * 64 + ks * 32 + quad * 8];
  __syncthreads();   // Qs free, Ks may overwrite

  const f32x4 Z4 = {0.f, 0.f, 0.f, 0.f};
  f32x4 O[2][4];
  float m_st[2][4], l_st[2][4];
#pragma unroll
  for (int mt = 0; mt < 2; mt++) {
#pragma unroll
    for (int nt = 0; nt < 4; nt++) O[mt][nt] = Z4;
#pragma unroll
    for (int r = 0; r < 4; r++) { m_st[mt][r] = -1e30f; l_st[mt][r] = 0.f; }
  }

  for (int kt = 0; kt < 16; kt++) {
    const int s0 = kt * 128;
#pragma unroll
    for (int i = 0; i < 4; i++)
      async16(Ks + i * 2048 + tid * 8,
              Kg + (size_t)(s0 + i * 32 + (tid >> 3)) * 64 + (tid & 7) * 8);
#pragma unroll
    for (int i = 0; i < 4; i++)
      async16(Vts + i * 2048 + tid * 8,
              Vg + (size_t)(i * 16 + (tid >> 4)) * 2048 + s0 + (tid & 15) * 8);
    __syncthreads();

    // S = Q K^T (pre-scaled by 1/8 via Q)
    f32x4 sc[2][8];
#pragma unroll
    for (int mt = 0; mt < 2; mt++)
#pragma unroll
      for (int nt = 0; nt < 8; nt++) sc[mt][nt] = Z4;
#pragma unroll
    for (int nt = 0; nt < 8; nt++) {
      bf16x8 kf0 = *(const bf16x8*)&Ks[(nt * 16 + l16) * 64 + quad * 8];
      bf16x8 kf1 = *(const bf16x8*)&Ks[(nt * 16 + l16) * 64 + 32 + quad * 8];
#pragma unroll
      for (int mt = 0; mt < 2; mt++) {
        sc[mt][nt] = __builtin_amdgcn_mfma_f32_16x16x32_bf16(qf[mt][0], kf0, sc[mt][nt], 0, 0, 0);
        sc[mt][nt] = __builtin_amdgcn_mfma_f32_16x16x32_bf16(qf[mt][1], kf1, sc[mt][nt], 0, 0, 0);
      }
    }

    // online softmax per row (row = quad*4+r; stats replicated over 16 lanes)
#pragma unroll
    for (int mt = 0; mt < 2; mt++)
#pragma unroll
      for (int r = 0; r < 4; r++) {
        float mx = sc[mt][0][r];
#pragma unroll
        for (int nt = 1; nt < 8; nt++) mx = fmaxf(mx, sc[mt][nt][r]);
#pragma unroll
        for (int off = 1; off < 16; off <<= 1) mx = fmaxf(mx, __shfl_xor(mx, off));
        float mold = m_st[mt][r];
        float mnew = fmaxf(mold, mx);
        m_st[mt][r] = mnew;
        float alpha = __builtin_amdgcn_exp2f((mold - mnew) * LOG2E);
        float psum = 0.f;
#pragma unroll
        for (int nt = 0; nt < 8; nt++) {
          float p = __builtin_amdgcn_exp2f((sc[mt][nt][r] - mnew) * LOG2E);
          sc[mt][nt][r] = p;
          psum += p;
        }
#pragma unroll
        for (int off = 1; off < 16; off <<= 1) psum += __shfl_xor(psum, off);
        l_st[mt][r] = l_st[mt][r] * alpha + psum;
#pragma unroll
        for (int nt = 0; nt < 4; nt++) O[mt][nt][r] *= alpha;
      }

    // P: C-layout regs -> A-operand layout via LDS (wave-private rows)
#pragma unroll
    for (int mt = 0; mt < 2; mt++)
#pragma unroll
      for (int nt = 0; nt < 8; nt++)
#pragma unroll
        for (int r = 0; r < 4; r++)
          Ps[(w * 32 + mt * 16 + quad * 4 + r) * 128 + nt * 16 + l16] =
              f2bf(sc[mt][nt][r]);
    __asm__ volatile("s_waitcnt lgkmcnt(0)" ::: "memory");

    // O += P V
#pragma unroll
    for (int ks = 0; ks < 4; ks++) {
      bf16x8 pf[2];
#pragma unroll
      for (int mt = 0; mt < 2; mt++)
        pf[mt] = *(const bf16x8*)&Ps[(w * 32 + mt * 16 + l16) * 128 + ks * 32 + quad * 8];
#pragma unroll
      for (int nt = 0; nt < 4; nt++) {
        bf16x8 vf = *(const bf16x8*)&Vts[(nt * 16 + l16) * 128 + ks * 32 + quad * 8];
#pragma unroll
        for (int mt = 0; mt < 2; mt++)
          O[mt][nt] = __builtin_amdgcn_mfma_f32_16x16x32_bf16(pf[mt], vf, O[mt][nt], 0, 0, 0);
      }
    }
    __syncthreads();   // Ks/Vts free for next tile
  }

  // epilogue: O/l * sigmoid(gate) -> act[b][s][h*64+d]
#pragma unroll
  for (int mt = 0; mt < 2; mt++) {
    float inv[4];
#pragma unroll
    for (int r = 0; r < 4; r++) inv[r] = 1.0f / l_st[mt][r];
#pragma unroll
    for (int nt = 0; nt < 4; nt++)
#pragma unroll
      for (int r = 0; r < 4; r++) {
        int srow = q0 + w * 32 + mt * 16 + quad * 4 + r;
        int col = h * 64 + nt * 16 + l16;
        size_t off = (size_t)(b * 2048 + srow) * 2048 + col;
        float g = bf2f(gate[off]);
        float sig = 1.0f / (1.0f + __builtin_amdgcn_exp2f(-g * LOG2E));
        act[off] = f2bf(O[mt][nt][r] * inv[r] * sig);
      }
  }
}

// ------------------------------------------------------------------ launcher
extern "C" void kernel_launch(void* const* d_in, const int* in_sizes, int n_in,
                              void* d_out, int out_size, void* d_ws, size_t ws_size,
                              hipStream_t stream) {
  const float* hid  = (const float*)d_in[0];
  const float* cosb = (const float*)d_in[1];
  const float* sinb = (const float*)d_in[2];
  const float* Wq   = (const float*)d_in[3];
  const float* Wk   = (const float*)d_in[4];
  const float* Wv   = (const float*)d_in[5];
  const float* Wg   = (const float*)d_in[6];
  const float* Wo   = (const float*)d_in[7];
  const float* qg   = (const float*)d_in[8];
  const float* kg   = (const float*)d_in[9];
  float* out = (float*)d_out;

  char* ws = (char*)d_ws;
  unsigned short* Xb   = (unsigned short*)(ws);              // 16,777,216 B
  unsigned short* WqB  = (unsigned short*)(ws + 16777216);   //  8,388,608
  unsigned short* WkB  = (unsigned short*)(ws + 25165824);   //  1,048,576
  unsigned short* WvB  = (unsigned short*)(ws + 26214400);   //  1,048,576
  unsigned short* WgB  = (unsigned short*)(ws + 27262976);   //  8,388,608
  unsigned short* WoB  = (unsigned short*)(ws + 35651584);   //  8,388,608
  unsigned short* Qraw = (unsigned short*)(ws + 44040192);   // 16,777,216
  unsigned short* Kraw = (unsigned short*)(ws + 60817408);   //  2,097,152
  unsigned short* Vraw = (unsigned short*)(ws + 62914560);   //  2,097,152
  unsigned short* gate = (unsigned short*)(ws + 65011712);   // 16,777,216
  unsigned short* Kn   = (unsigned short*)(ws + 81788928);   //  2,097,152
  unsigned short* Vt   = (unsigned short*)(ws + 83886080);   //  2,097,152
  // region reuse (strictly ordered by stream):
  unsigned short* Qn  = Xb;    // Xb dead after gemm_qkvg
  unsigned short* act = WqB;   // Wq..Wg bf16 dead after gemm_qkvg (Wo is NOT overlapped)

  // f32 -> bf16
  {
    struct { const float* s; unsigned short* d; int n; } jobs[6] = {
      {hid, Xb, 8388608}, {Wq, WqB, 4194304}, {Wk, WkB, 524288},
      {Wv, WvB, 524288}, {Wg, WgB, 4194304}, {Wo, WoB, 4194304}};
    for (int i = 0; i < 6; i++) {
      int n4 = jobs[i].n / 4;
      cvt_f32_bf16<<<dim3((n4 + 255) / 256), dim3(256), 0, stream>>>(
          jobs[i].s, jobs[i].d, n4);
    }
  }

  gemm_qkvg<<<dim3(32, 36), dim3(256), 0, stream>>>(
      Xb, WqB, WkB, WvB, WgB, Qraw, Kraw, Vraw, gate);

  prep_qkv<<<dim3(40960), dim3(256), 0, stream>>>(
      Qraw, Kraw, Vraw, cosb, sinb, qg, kg, Qn, Kn, Vt);

  attn<<<dim3(16, 64), dim3(256), 0, stream>>>(Qn, Kn, Vt, gate, act);

  gemm_out_k<<<dim3(32, 16), dim3(256), 0, stream>>>(act, WoB, out);
}

// Round 2
// 507.695 us; speedup vs baseline: 1.1148x; 1.1148x over previous
//
#include <hip/hip_runtime.h>

// AfmoeAttention on MI355X (gfx950), round 2.
// Change vs r1: attention LDS bank-conflict fix (XOR chunk swizzles on
// Ks/Vts/Ps), Ps overlaid on Ks region (two kv-halves) -> 32 KB LDS,
// 4 blocks/CU occupancy. GEMM/prep/cvt kernels unchanged.

#define LOG2E 1.44269504088896340736f

typedef __attribute__((ext_vector_type(4))) float f32x4;
typedef __attribute__((ext_vector_type(8))) short bf16x8;   // 8 x bf16 (4 VGPRs)

__device__ __forceinline__ float bf2f(unsigned short u) {
  union { unsigned u; float f; } x; x.u = ((unsigned)u) << 16; return x.f;
}
__device__ __forceinline__ unsigned short f2bf(float f) {
  union { float f; unsigned u; } x; x.f = f;
  unsigned r = x.u + 0x7fffu + ((x.u >> 16) & 1u);   // RNE
  return (unsigned short)(r >> 16);
}

// async global->LDS, 16B per lane. LDS dest = wave-uniform base + lane*16.
__device__ __forceinline__ void async16(void* lds, const void* g) {
  __builtin_amdgcn_global_load_lds(
      (const __attribute__((address_space(1))) unsigned*)g,
      (__attribute__((address_space(3))) unsigned*)lds, 16, 0, 0);
}
__device__ __forceinline__ void lds_fence() {
  __asm__ volatile("s_waitcnt lgkmcnt(0)" ::: "memory");
}

// ---------------------------------------------------------------- cvt kernel
__global__ __launch_bounds__(256) void cvt_f32_bf16(
    const float* __restrict__ src, unsigned short* __restrict__ dst, int n4) {
  int i = blockIdx.x * 256 + threadIdx.x;
  if (i >= n4) return;
  float4 v = reinterpret_cast<const float4*>(src)[i];
  ushort4 u;
  u.x = f2bf(v.x); u.y = f2bf(v.y); u.z = f2bf(v.z); u.w = f2bf(v.w);
  reinterpret_cast<ushort4*>(dst)[i] = u;
}

// ------------------------------------------------------------- GEMM template
// C[M,N] = A[M,K] @ W[N,K]^T, 128x128 tile, BK=32, 4 waves each 64x64.
template <typename CT>
__device__ __forceinline__ void gemm128(
    const unsigned short* __restrict__ A, const unsigned short* __restrict__ W,
    CT* __restrict__ C, int m0, int n0, int ldc, int K,
    unsigned short* As, unsigned short* Bs) {
  const int tid = threadIdx.x;
  const int w = tid >> 6, l = tid & 63, quad = l >> 4, l16 = l & 15;
  const int wm = (w & 1) * 64, wn = (w >> 1) * 64;

  f32x4 acc[4][4];
  const f32x4 Z4 = {0.f, 0.f, 0.f, 0.f};
#pragma unroll
  for (int i = 0; i < 4; i++)
#pragma unroll
    for (int j = 0; j < 4; j++) acc[i][j] = Z4;

  const int srow = tid >> 2;            // 0..63
  const int scol = (tid & 3) * 8;       // elem offset in K
  const unsigned short* gA = A + (size_t)(m0 + srow) * K + scol;
  const unsigned short* gB = W + (size_t)(n0 + srow) * K + scol;
  unsigned short* lA = As + tid * 8;    // byte offset tid*16
  unsigned short* lB = Bs + tid * 8;

  for (int kb = 0; kb < K; kb += 32) {
    async16(lA,        gA + kb);
    async16(lA + 2048, gA + (size_t)64 * K + kb);
    async16(lB,        gB + kb);
    async16(lB + 2048, gB + (size_t)64 * K + kb);
    __syncthreads();   // waits vmcnt(0): async LDS writes landed

    bf16x8 af[4], bf[4];
#pragma unroll
    for (int mt = 0; mt < 4; mt++)
      af[mt] = *(const bf16x8*)&As[(wm + mt * 16 + l16) * 32 + quad * 8];
#pragma unroll
    for (int nt = 0; nt < 4; nt++)
      bf[nt] = *(const bf16x8*)&Bs[(wn + nt * 16 + l16) * 32 + quad * 8];
#pragma unroll
    for (int mt = 0; mt < 4; mt++)
#pragma unroll
      for (int nt = 0; nt < 4; nt++)
        acc[mt][nt] = __builtin_amdgcn_mfma_f32_16x16x32_bf16(
            af[mt], bf[nt], acc[mt][nt], 0, 0, 0);
    __syncthreads();   // all reads done before next tile's staging
  }

  // C/D layout: col = lane&15, row = quad*4 + reg
#pragma unroll
  for (int mt = 0; mt < 4; mt++)
#pragma unroll
    for (int nt = 0; nt < 4; nt++) {
      int row = m0 + wm + mt * 16 + quad * 4;
      int col = n0 + wn + nt * 16 + l16;
#pragma unroll
      for (int r = 0; r < 4; r++) {
        if constexpr (sizeof(CT) == 2)
          C[(size_t)(row + r) * ldc + col] = f2bf(acc[mt][nt][r]);
        else
          C[(size_t)(row + r) * ldc + col] = acc[mt][nt][r];
      }
    }
}

__global__ __launch_bounds__(256) void gemm_qkvg(
    const unsigned short* __restrict__ X,
    const unsigned short* __restrict__ Wq, const unsigned short* __restrict__ Wk,
    const unsigned short* __restrict__ Wv, const unsigned short* __restrict__ Wg,
    unsigned short* __restrict__ Qr, unsigned short* __restrict__ Kr,
    unsigned short* __restrict__ Vr, unsigned short* __restrict__ Gr) {
  __shared__ __attribute__((aligned(16))) unsigned short As[128 * 32];
  __shared__ __attribute__((aligned(16))) unsigned short Bs[128 * 32];
  int ny = blockIdx.y;
  const unsigned short* W; unsigned short* C; int n0, ldc;
  if (ny < 16)      { W = Wq; C = Qr; n0 = ny * 128;        ldc = 2048; }
  else if (ny < 18) { W = Wk; C = Kr; n0 = (ny - 16) * 128; ldc = 256;  }
  else if (ny < 20) { W = Wv; C = Vr; n0 = (ny - 18) * 128; ldc = 256;  }
  else              { W = Wg; C = Gr; n0 = (ny - 20) * 128; ldc = 2048; }
  gemm128<unsigned short>(X, W, C, blockIdx.x * 128, n0, ldc, 2048, As, Bs);
}

__global__ __launch_bounds__(256) void gemm_out_k(
    const unsigned short* __restrict__ A, const unsigned short* __restrict__ W,
    float* __restrict__ C) {
  __shared__ __attribute__((aligned(16))) unsigned short As[128 * 32];
  __shared__ __attribute__((aligned(16))) unsigned short Bs[128 * 32];
  gemm128<float>(A, W, C, blockIdx.x * 128, blockIdx.y * 128, 2048, 2048, As, Bs);
}

// ------------------------------------------------------ RMSNorm+RoPE+transpose
__global__ __launch_bounds__(256) void prep_qkv(
    const unsigned short* __restrict__ Qr, const unsigned short* __restrict__ Kr,
    const unsigned short* __restrict__ Vr,
    const float* __restrict__ cosb, const float* __restrict__ sinb,
    const float* __restrict__ qg, const float* __restrict__ kg,
    unsigned short* __restrict__ Qn, unsigned short* __restrict__ Kn,
    unsigned short* __restrict__ Vt) {
  int idx = blockIdx.x * 4 + (threadIdx.x >> 6);   // global unit index
  int d = threadIdx.x & 63;
  int token = idx / 40;
  int unit = idx - token * 40;
  int b = token >> 11, s = token & 2047;

  if (unit >= 36) {   // V transpose (scattered 2B stores, small total)
    int kvh = unit - 36;
    Vt[((size_t)(b * 4 + kvh) * 64 + d) * 2048 + s] =
        Vr[(size_t)token * 256 + kvh * 64 + d];
    return;
  }
  const unsigned short* src; const float* gamma; float scale; unsigned short* dst;
  if (unit < 32) {
    src = Qr + (size_t)token * 2048 + unit * 64;
    gamma = qg; scale = 0.125f;               // 1/sqrt(D)
    dst = Qn + ((size_t)(b * 32 + unit) * 2048 + s) * 64;
  } else {
    int kvh = unit - 32;
    src = Kr + (size_t)token * 256 + kvh * 64;
    gamma = kg; scale = 1.0f;
    dst = Kn + ((size_t)(b * 4 + kvh) * 2048 + s) * 64;
  }
  float x = bf2f(src[d]);
  float ss = x * x;
#pragma unroll
  for (int off = 32; off >= 1; off >>= 1) ss += __shfl_xor(ss, off);
  float rr = rsqrtf(ss * (1.0f / 64.0f) + 1e-6f);
  float xn = x * rr * gamma[d];
  float other = __shfl_xor(xn, 32);           // partner at d^32
  float rot = (d < 32) ? -other : other;      // rotate_half
  size_t cs = (size_t)(b * 2048 + s) * 64 + d;
  dst[d] = f2bf((xn * cosb[cs] + rot * sinb[cs]) * scale);
}

// ---------------------------------------------------------- flash attention
// grid: (S/128, B*NH). 4 waves, each owns 32 Q rows. KV tiles of 128.
// LDS 32 KB: Ks[128][64] (swizzled, also hosts Qs in prologue and Ps
// per-wave after QK), Vts[64][128] (swizzled).
// Swizzles (16B chunk granularity):
//   Ks/Qs: phys_chunk = data_chunk ^ (row & 7)    (8 chunks/row)
//   Vts:   phys_chunk = data_chunk ^ (row & 15)   (16 chunks/row)
//   Ps:    per-wave [32 q][64 kv], phys_chunk = data_chunk ^ (q & 7)
__global__ __launch_bounds__(256) void attn(
    const unsigned short* __restrict__ Qn, const unsigned short* __restrict__ Kn,
    const unsigned short* __restrict__ Vt, const unsigned short* __restrict__ gate,
    unsigned short* __restrict__ act) {
  __shared__ __attribute__((aligned(16))) unsigned short smem[16384];  // 32 KB
  unsigned short* Ks  = smem;           // [128][64] sw; Qs prologue; Ps halves
  unsigned short* Vts = smem + 8192;    // [64][128] sw

  const int tid = threadIdx.x, w = tid >> 6, l = tid & 63;
  const int quad = l >> 4, l16 = l & 15;
  const int l7 = l16 & 7, l8 = l16 >> 3;
  const int bh = blockIdx.y, b = bh >> 5, h = bh & 31, kvh = h >> 3;
  const int q0 = blockIdx.x * 128;

  const unsigned short* Qg = Qn + ((size_t)(b * 32 + h) * 2048 + q0) * 64;
  const unsigned short* Kg = Kn + (size_t)(b * 4 + kvh) * 2048 * 64;
  const unsigned short* Vg = Vt + (size_t)(b * 4 + kvh) * 64 * 2048;

  // swizzled staging source chunk indices
  const int kq_src = ((tid & 7) ^ ((tid >> 3) & 7)) * 8;   // K/Q staging
  const int v_src  = (((tid & 15) ^ (tid >> 4)) & 15) * 8; // V staging

  // ---- prologue: stage Q (swizzled), read q-fragments
#pragma unroll
  for (int i = 0; i < 4; i++)
    async16(Ks + i * 2048 + tid * 8,
            Qg + (size_t)(i * 32 + (tid >> 3)) * 64 + kq_src);
  __syncthreads();
  bf16x8 qf[2][2];
#pragma unroll
  for (int mt = 0; mt < 2; mt++)
#pragma unroll
    for (int ks = 0; ks < 2; ks++) {
      int row = w * 32 + mt * 16 + l16;
      int p = (ks * 4 + quad) ^ l7;
      qf[mt][ks] = *(const bf16x8*)&Ks[row * 64 + p * 8];
    }
  __syncthreads();   // Qs region free

  const f32x4 Z4 = {0.f, 0.f, 0.f, 0.f};
  f32x4 O[2][4];
  float m_st[2][4], l_st[2][4];
#pragma unroll
  for (int mt = 0; mt < 2; mt++) {
#pragma unroll
    for (int nt = 0; nt < 4; nt++) O[mt][nt] = Z4;
#pragma unroll
    for (int r = 0; r < 4; r++) { m_st[mt][r] = -1e30f; l_st[mt][r] = 0.f; }
  }

  unsigned short* Pw = Ks + w * 2048;   // wave-private P region, 4 KB

  for (int kt = 0; kt < 16; kt++) {
    const int s0 = kt * 128;
#pragma unroll
    for (int i = 0; i < 4; i++)
      async16(Ks + i * 2048 + tid * 8,
              Kg + (size_t)(s0 + i * 32 + (tid >> 3)) * 64 + kq_src);
#pragma unroll
    for (int i = 0; i < 4; i++)
      async16(Vts + i * 2048 + tid * 8,
              Vg + (size_t)(i * 16 + (tid >> 4)) * 2048 + s0 + v_src);
    __syncthreads();

    // ---- S = Q K^T (pre-scaled by 1/8 via Q)
    f32x4 sc[2][8];
#pragma unroll
    for (int mt = 0; mt < 2; mt++)
#pragma unroll
      for (int nt = 0; nt < 8; nt++) sc[mt][nt] = Z4;
#pragma unroll
    for (int nt = 0; nt < 8; nt++) {
      int row = nt * 16 + l16;
      bf16x8 kf0 = *(const bf16x8*)&Ks[row * 64 + (quad ^ l7) * 8];
      bf16x8 kf1 = *(const bf16x8*)&Ks[row * 64 + ((4 + quad) ^ l7) * 8];
#pragma unroll
      for (int mt = 0; mt < 2; mt++) {
        sc[mt][nt] = __builtin_amdgcn_mfma_f32_16x16x32_bf16(qf[mt][0], kf0, sc[mt][nt], 0, 0, 0);
        sc[mt][nt] = __builtin_amdgcn_mfma_f32_16x16x32_bf16(qf[mt][1], kf1, sc[mt][nt], 0, 0, 0);
      }
    }
    __syncthreads();   // all waves done reading Ks; Ps may overwrite

    // ---- online softmax (stats replicated over 16 lanes)
#pragma unroll
    for (int mt = 0; mt < 2; mt++)
#pragma unroll
      for (int r = 0; r < 4; r++) {
        float mx = sc[mt][0][r];
#pragma unroll
        for (int nt = 1; nt < 8; nt++) mx = fmaxf(mx, sc[mt][nt][r]);
#pragma unroll
        for (int off = 1; off < 16; off <<= 1) mx = fmaxf(mx, __shfl_xor(mx, off));
        float mold = m_st[mt][r];
        float mnew = fmaxf(mold, mx);
        m_st[mt][r] = mnew;
        float alpha = __builtin_amdgcn_exp2f((mold - mnew) * LOG2E);
        float psum = 0.f;
#pragma unroll
        for (int nt = 0; nt < 8; nt++) {
          float p = __builtin_amdgcn_exp2f((sc[mt][nt][r] - mnew) * LOG2E);
          sc[mt][nt][r] = p;
          psum += p;
        }
#pragma unroll
        for (int off = 1; off < 16; off <<= 1) psum += __shfl_xor(psum, off);
        l_st[mt][r] = l_st[mt][r] * alpha + psum;
#pragma unroll
        for (int nt = 0; nt < 4; nt++) O[mt][nt][r] *= alpha;
      }

    // ---- P V in two kv-halves through wave-private swizzled Ps
#pragma unroll
    for (int hh = 0; hh < 2; hh++) {
#pragma unroll
      for (int mt = 0; mt < 2; mt++)
#pragma unroll
        for (int ntl = 0; ntl < 4; ntl++) {
          int c = ntl * 2 + l8;
#pragma unroll
          for (int r = 0; r < 4; r++) {
            int q = mt * 16 + quad * 4 + r;
            int p = c ^ (q & 7);
            Pw[q * 64 + p * 8 + l7] = f2bf(sc[mt][hh * 4 + ntl][r]);
          }
        }
      lds_fence();   // writes visible before reads
#pragma unroll
      for (int ksl = 0; ksl < 2; ksl++) {
        int ks = hh * 2 + ksl;
        bf16x8 pf[2];
#pragma unroll
        for (int mt = 0; mt < 2; mt++) {
          int q = mt * 16 + l16;
          int p = (ksl * 4 + quad) ^ (q & 7);
          pf[mt] = *(const bf16x8*)&Pw[q * 64 + p * 8];
        }
#pragma unroll
        for (int nt = 0; nt < 4; nt++) {
          int row = nt * 16 + l16;
          int p = ((ks * 4 + quad) ^ (row & 15));
          bf16x8 vf = *(const bf16x8*)&Vts[row * 128 + p * 8];
#pragma unroll
          for (int mt = 0; mt < 2; mt++)
            O[mt][nt] = __builtin_amdgcn_mfma_f32_16x16x32_bf16(pf[mt], vf, O[mt][nt], 0, 0, 0);
        }
      }
      lds_fence();   // half-1 reads retired before half-2 overwrites
    }
    __syncthreads();   // Ks(=Ps)/Vts free for next tile's staging
  }

  // ---- epilogue: O/l * sigmoid(gate) -> act[b][s][h*64+d]
#pragma unroll
  for (int mt = 0; mt < 2; mt++) {
    float inv[4];
#pragma unroll
    for (int r = 0; r < 4; r++) inv[r] = 1.0f / l_st[mt][r];
#pragma unroll
    for (int nt = 0; nt < 4; nt++)
#pragma unroll
      for (int r = 0; r < 4; r++) {
        int srow = q0 + w * 32 + mt * 16 + quad * 4 + r;
        int col = h * 64 + nt * 16 + l16;
        size_t off = (size_t)(b * 2048 + srow) * 2048 + col;
        float g = bf2f(gate[off]);
        float sig = 1.0f / (1.0f + __builtin_amdgcn_exp2f(-g * LOG2E));
        act[off] = f2bf(O[mt][nt][r] * inv[r] * sig);
      }
  }
}

// ------------------------------------------------------------------ launcher
extern "C" void kernel_launch(void* const* d_in, const int* in_sizes, int n_in,
                              void* d_out, int out_size, void* d_ws, size_t ws_size,
                              hipStream_t stream) {
  const float* hid  = (const float*)d_in[0];
  const float* cosb = (const float*)d_in[1];
  const float* sinb = (const float*)d_in[2];
  const float* Wq   = (const float*)d_in[3];
  const float* Wk   = (const float*)d_in[4];
  const float* Wv   = (const float*)d_in[5];
  const float* Wg   = (const float*)d_in[6];
  const float* Wo   = (const float*)d_in[7];
  const float* qg   = (const float*)d_in[8];
  const float* kg   = (const float*)d_in[9];
  float* out = (float*)d_out;

  char* ws = (char*)d_ws;
  unsigned short* Xb   = (unsigned short*)(ws);              // 16,777,216 B
  unsigned short* WqB  = (unsigned short*)(ws + 16777216);   //  8,388,608
  unsigned short* WkB  = (unsigned short*)(ws + 25165824);   //  1,048,576
  unsigned short* WvB  = (unsigned short*)(ws + 26214400);   //  1,048,576
  unsigned short* WgB  = (unsigned short*)(ws + 27262976);   //  8,388,608
  unsigned short* WoB  = (unsigned short*)(ws + 35651584);   //  8,388,608
  unsigned short* Qraw = (unsigned short*)(ws + 44040192);   // 16,777,216
  unsigned short* Kraw = (unsigned short*)(ws + 60817408);   //  2,097,152
  unsigned short* Vraw = (unsigned short*)(ws + 62914560);   //  2,097,152
  unsigned short* gate = (unsigned short*)(ws + 65011712);   // 16,777,216
  unsigned short* Kn   = (unsigned short*)(ws + 81788928);   //  2,097,152
  unsigned short* Vt   = (unsigned short*)(ws + 83886080);   //  2,097,152
  // region reuse (strictly ordered by stream):
  unsigned short* Qn  = Xb;    // Xb dead after gemm_qkvg
  unsigned short* act = WqB;   // Wq..Wg bf16 dead after gemm_qkvg

  // f32 -> bf16
  {
    struct { const float* s; unsigned short* d; int n; } jobs[6] = {
      {hid, Xb, 8388608}, {Wq, WqB, 4194304}, {Wk, WkB, 524288},
      {Wv, WvB, 524288}, {Wg, WgB, 4194304}, {Wo, WoB, 4194304}};
    for (int i = 0; i < 6; i++) {
      int n4 = jobs[i].n / 4;
      cvt_f32_bf16<<<dim3((n4 + 255) / 256), dim3(256), 0, stream>>>(
          jobs[i].s, jobs[i].d, n4);
    }
  }

  gemm_qkvg<<<dim3(32, 36), dim3(256), 0, stream>>>(
      Xb, WqB, WkB, WvB, WgB, Qraw, Kraw, Vraw, gate);

  prep_qkv<<<dim3(40960), dim3(256), 0, stream>>>(
      Qraw, Kraw, Vraw, cosb, sinb, qg, kg, Qn, Kn, Vt);

  attn<<<dim3(16, 64), dim3(256), 0, stream>>>(Qn, Kn, Vt, gate, act);

  gemm_out_k<<<dim3(32, 16), dim3(256), 0, stream>>>(act, WoB, out);
}